// Round 18
// baseline (561.879 us; speedup 1.0000x reference)
//
#include <hip/hip_runtime.h>
#include <math.h>

#pragma clang fp contract(off)

#define NPIX 4096
#define BIGF 3.0e38f
#define SLOTS 8

// ---------------- helpers ----------------

// value-only sorted insert (ascending) into top-5
__device__ __forceinline__ void ins5v(float v, float dl[5]) {
    if (v >= dl[4]) return;
    dl[4] = v;
#pragma unroll
    for (int u = 4; u > 0; --u)
        if (dl[u] < dl[u - 1]) { float t_ = dl[u]; dl[u] = dl[u - 1]; dl[u - 1] = t_; }
}

// np.logaddexp(x, 0) emulation: scalar libm path, fp64-rounded (≈correctly rounded fp32)
__device__ __forceinline__ float softplus_np(float x) {
    if (x > 0.f) {
        float ef = (float)exp((double)(-x));
        return x + (float)log1p((double)ef);
    } else if (x < 0.f) {
        float ef = (float)exp((double)x);
        return (float)log1p((double)ef);
    }
    return 0.69314718055994530942f;
}

// ---------------- fused GEMM + BN + relu (np op order), z-batched pair ----------

__global__ __launch_bounds__(256) void gemm_bn_relu2_kernel(
    const float* __restrict__ W,
    const float* __restrict__ Xa, const float* __restrict__ Xb,
    const float* __restrict__ b, const float* __restrict__ g,
    const float* __restrict__ be, const float* __restrict__ m,
    const float* __restrict__ v,
    float* __restrict__ Ha, float* __restrict__ Hb, int M, int K) {
    const float* X = blockIdx.z ? Xb : Xa;
    float* H = blockIdx.z ? Hb : Ha;
    __shared__ float Ws[16][68];
    __shared__ float Xs[16][68];
    int t = threadIdx.x;
    int tx = t & 15, ty = t >> 4;
    int n0 = blockIdx.x * 64, m0 = blockIdx.y * 64;
    int wm = t >> 2, wk = (t & 3) * 4;
    int xk = t >> 4, xn = (t & 15) * 4;
    float acc[4][4] = {};
    for (int k0 = 0; k0 < K; k0 += 16) {
        float4 wv = *(const float4*)&W[(size_t)(m0 + wm) * K + k0 + wk];
        Ws[wk + 0][wm] = wv.x; Ws[wk + 1][wm] = wv.y;
        Ws[wk + 2][wm] = wv.z; Ws[wk + 3][wm] = wv.w;
        *(float4*)&Xs[xk][xn] = *(const float4*)&X[(size_t)(k0 + xk) * NPIX + n0 + xn];
        __syncthreads();
#pragma unroll
        for (int kk = 0; kk < 16; ++kk) {
            float4 a4 = *(float4*)&Ws[kk][ty * 4];
            float4 b4 = *(float4*)&Xs[kk][tx * 4];
            float ar[4] = {a4.x, a4.y, a4.z, a4.w};
            float br[4] = {b4.x, b4.y, b4.z, b4.w};
#pragma unroll
            for (int i = 0; i < 4; ++i)
#pragma unroll
                for (int j = 0; j < 4; ++j)
                    acc[i][j] = fmaf(ar[i], br[j], acc[i][j]);
        }
        __syncthreads();
    }
#pragma unroll
    for (int i = 0; i < 4; ++i) {
        int mrow = m0 + ty * 4 + i;
        float bb = b[mrow];
        float mm_ = m[mrow];
        float gg = g[mrow];
        float vv = v[mrow] + 1e-5f;
        float ss = (float)sqrt((double)vv);
        float bee = be[mrow];
        float o[4];
#pragma unroll
        for (int j = 0; j < 4; ++j) {
            float t0 = acc[i][j] + bb;
            t0 = t0 - mm_;
            t0 = t0 * gg;
            t0 = (float)((double)t0 / (double)ss);
            t0 = t0 + bee;
            o[j] = fmaxf(t0, 0.f);
        }
        *(float4*)&H[(size_t)mrow * NPIX + n0 + tx * 4] = *(float4*)&o[0];
    }
}

// ---------------- qs/ks: sequential fp32 FMA dot + bias at end, z-batched --------

__global__ void dotk_np2_kernel(const float* __restrict__ Ha, const float* __restrict__ Hb,
                                const float* __restrict__ cwa, const float* __restrict__ cba,
                                const float* __restrict__ cwb, const float* __restrict__ cbb,
                                float* __restrict__ outa, float* __restrict__ outb, int C) {
    const float* H = blockIdx.z ? Hb : Ha;
    const float* cw = blockIdx.z ? cwb : cwa;
    const float* cb = blockIdx.z ? cbb : cba;
    float* out = blockIdx.z ? outb : outa;
    int p = blockIdx.x * 256 + threadIdx.x;
    float s = 0.f;
#pragma unroll 8
    for (int c = 0; c < C; ++c) s = fmaf(H[(size_t)c * NPIX + p], cw[c], s);
    out[p] = s + cb[0];
}

// ---------------- skn: numpy pairwise sum, 128-blocks computed in parallel -------

__global__ void skn_np2_kernel(const float* __restrict__ Ya, const float* __restrict__ Yb,
                               float* __restrict__ skna, float* __restrict__ sknb, int C) {
    const float* Y = blockIdx.z ? Yb : Ya;
    float* skn = blockIdx.z ? sknb : skna;
    int nb = C >> 7;                 // 2 or 4
    int ppb = 256 / nb;              // p's per block
    int t = threadIdx.x;
    int pl = t % ppb;
    int b = t / ppb;
    int p = blockIdx.x * ppb + pl;
    __shared__ float sh[256];

    int c0 = b << 7;
    float r[8];
#pragma unroll
    for (int k = 0; k < 8; ++k) {
        float y = Y[(size_t)(c0 + k) * NPIX + p];
        r[k] = y * y;
    }
    for (int i = 8; i < 128; i += 8) {
#pragma unroll
        for (int k = 0; k < 8; ++k) {
            float y = Y[(size_t)(c0 + i + k) * NPIX + p];
            float q = y * y;
            r[k] = r[k] + q;
        }
    }
    sh[b * ppb + pl] = ((r[0] + r[1]) + (r[2] + r[3])) + ((r[4] + r[5]) + (r[6] + r[7]));
    __syncthreads();
    if (b == 0) {
        float s;
        if (nb == 2) s = sh[pl] + sh[ppb + pl];
        else s = (sh[pl] + sh[ppb + pl]) + (sh[2 * ppb + pl] + sh[3 * ppb + pl]);
        skn[p] = s;
    }
}

// ---------------- distance: np-exact fp32, 64x128 tile, 4x8 micro, dbuf LDS -----
// Double-buffered: ONE barrier per c-tile; prefetch->LDS write lands after compute.
// Slot-padded layouts keep all hot-loop LDS reads <=2-way (free).
// Per (q,k): fp32 FMA over c ascending — identical arithmetic to R10's passing kernel.

__global__ __launch_bounds__(256) void dist_np_kernel(
    const float* __restrict__ XT, const float* __restrict__ YT,
    const float* __restrict__ sknq, const float* __restrict__ sknk,
    float* __restrict__ D, int C, int qbase) {
    __shared__ float Xs[2][16][68];
    __shared__ float Ys[2][16][16][12];
    int t = threadIdx.x;
    int tx = t & 15, ty = t >> 4;
    int q0 = qbase + blockIdx.y * 64;
    int k0 = blockIdx.x * 128;
    float acc[4][8] = {};
    // stage tile 0
    float4 xr = *(const float4*)&XT[(size_t)ty * NPIX + q0 + tx * 4];
    float4 yr0 = *(const float4*)&YT[(size_t)ty * NPIX + k0 + tx * 8];
    float4 yr1 = *(const float4*)&YT[(size_t)ty * NPIX + k0 + tx * 8 + 4];
    *(float4*)&Xs[0][ty][tx * 4] = xr;
    *(float4*)&Ys[0][ty][tx][0] = yr0;
    *(float4*)&Ys[0][ty][tx][4] = yr1;
    __syncthreads();
    int nt = C >> 4;
    for (int tt2 = 0; tt2 < nt; ++tt2) {
        int cur = tt2 & 1;
        if (tt2 + 1 < nt) {
            int cn = (tt2 + 1) << 4;
            xr = *(const float4*)&XT[(size_t)(cn + ty) * NPIX + q0 + tx * 4];
            yr0 = *(const float4*)&YT[(size_t)(cn + ty) * NPIX + k0 + tx * 8];
            yr1 = *(const float4*)&YT[(size_t)(cn + ty) * NPIX + k0 + tx * 8 + 4];
        }
#pragma unroll
        for (int kk = 0; kk < 16; ++kk) {
            float4 a4 = *(float4*)&Xs[cur][kk][ty * 4];
            float4 b40 = *(float4*)&Ys[cur][kk][tx][0];
            float4 b41 = *(float4*)&Ys[cur][kk][tx][4];
            float ar[4] = {a4.x, a4.y, a4.z, a4.w};
            float br[8] = {b40.x, b40.y, b40.z, b40.w, b41.x, b41.y, b41.z, b41.w};
#pragma unroll
            for (int i = 0; i < 4; ++i)
#pragma unroll
                for (int j = 0; j < 8; ++j)
                    acc[i][j] = fmaf(ar[i], br[j], acc[i][j]);
        }
        if (tt2 + 1 < nt) {
            *(float4*)&Xs[cur ^ 1][ty][tx * 4] = xr;
            *(float4*)&Ys[cur ^ 1][ty][tx][0] = yr0;
            *(float4*)&Ys[cur ^ 1][ty][tx][4] = yr1;
        }
        __syncthreads();
    }
    float sk8[8];
    *(float4*)&sk8[0] = *(const float4*)&sknk[k0 + tx * 8];
    *(float4*)&sk8[4] = *(const float4*)&sknk[k0 + tx * 8 + 4];
#pragma unroll
    for (int i = 0; i < 4; ++i) {
        float sq = sknq[q0 + ty * 4 + i];
        int lq = q0 - qbase + ty * 4 + i;
        float tmp[8];
#pragma unroll
        for (int j = 0; j < 8; ++j) {
            float A = sq + sk8[j];
            float B = 2.0f * acc[i][j];
            float d2 = A - B;
            float dc = fmaxf(d2, 0.f);
            tmp[j] = (float)sqrt((double)dc);
        }
        *(float4*)&D[(size_t)lq * NPIX + k0 + tx * 8] = *(float4*)&tmp[0];
        *(float4*)&D[(size_t)lq * NPIX + k0 + tx * 8 + 4] = *(float4*)&tmp[4];
    }
}

// ---------------- selection + np-softmax weights ----------------
// float4 D reads (thread->value assignment free: kth is a multiset statistic,
// kept set re-sorted by index); 3-level merge tree. 8 slots (census: n==5 always).

__global__ __launch_bounds__(256) void row_select_np_kernel(
    const float* __restrict__ D, const float* __restrict__ qs, const float* __restrict__ ks,
    int* __restrict__ isel, float* __restrict__ wsel, int qbase) {
    int p = qbase + blockIdx.x;
    const float* drow = D + (size_t)blockIdx.x * NPIX;
    int t = threadIdx.x;
    __shared__ float tops[256][5];
    __shared__ float l2[64][5];
    __shared__ float l3[16][5];
    __shared__ float kth_sh;
    __shared__ int cnt;
    __shared__ int slotj[16];
    __shared__ int n_sh;
    __shared__ float as_[16];
    __shared__ float evs[16];
    __shared__ float mx_sh, ssum_sh;

    if (t == 0) cnt = 0;
    float vcache[16];
    *(float4*)&vcache[0] = *(const float4*)&drow[t * 16];
    *(float4*)&vcache[4] = *(const float4*)&drow[t * 16 + 4];
    *(float4*)&vcache[8] = *(const float4*)&drow[t * 16 + 8];
    *(float4*)&vcache[12] = *(const float4*)&drow[t * 16 + 12];
    float dl[5] = {BIGF, BIGF, BIGF, BIGF, BIGF};
#pragma unroll
    for (int u = 0; u < 16; ++u) ins5v(vcache[u], dl);
#pragma unroll
    for (int u = 0; u < 5; ++u) tops[t][u] = dl[u];
    __syncthreads();
    if (t < 64) {
        float md[5] = {BIGF, BIGF, BIGF, BIGF, BIGF};
        for (int i = 0; i < 4; ++i)
            for (int u = 0; u < 5; ++u) ins5v(tops[t * 4 + i][u], md);
#pragma unroll
        for (int u = 0; u < 5; ++u) l2[t][u] = md[u];
    }
    __syncthreads();
    if (t < 16) {
        float md[5] = {BIGF, BIGF, BIGF, BIGF, BIGF};
        for (int i = 0; i < 4; ++i)
            for (int u = 0; u < 5; ++u) ins5v(l2[t * 4 + i][u], md);
#pragma unroll
        for (int u = 0; u < 5; ++u) l3[t][u] = md[u];
    }
    __syncthreads();
    if (t == 0) {
        float md[5] = {BIGF, BIGF, BIGF, BIGF, BIGF};
        for (int i = 0; i < 16; ++i)
            for (int u = 0; u < 5; ++u) ins5v(l3[i][u], md);
        kth_sh = md[4];
    }
    __syncthreads();
    float kth = kth_sh;
#pragma unroll
    for (int u = 0; u < 16; ++u) {
        if (vcache[u] <= kth) {
            int s = atomicAdd(&cnt, 1);
            if (s < 16) slotj[s] = t * 16 + u;
        }
    }
    __syncthreads();
    if (t == 0) {
        int n = cnt < 16 ? cnt : 16;
        for (int a = 1; a < n; ++a) {
            int key = slotj[a]; int b = a - 1;
            while (b >= 0 && slotj[b] > key) { slotj[b + 1] = slotj[b]; --b; }
            slotj[b + 1] = key;
        }
        n_sh = n;
    }
    __syncthreads();
    int n = n_sh;
    if (t < n) {
        float x = qs[p] + ks[slotj[t]];
        as_[t] = softplus_np(x);          // same formula, same input -> same bits
    }
    __syncthreads();
    if (t == 0) {
        float mx = -BIGF;
        for (int s = 0; s < n; ++s) mx = fmaxf(mx, as_[s]);
        mx_sh = mx;
    }
    __syncthreads();
    if (t < n) evs[t] = (float)exp((double)(as_[t] - mx_sh));
    __syncthreads();
    if (t == 0) {
        // numpy pairwise-tree sum over the sparse 4096-row (zeros absorb exactly)
        float bs[32];
        for (int i = 0; i < 32; ++i) bs[i] = 0.f;
        int s2 = 0;
        while (s2 < n) {
            int b = slotj[s2] >> 7;
            float r[8] = {0.f, 0.f, 0.f, 0.f, 0.f, 0.f, 0.f, 0.f};
            while (s2 < n && (slotj[s2] >> 7) == b) {
                int res = slotj[s2] & 7;
                r[res] = r[res] + evs[s2];
                ++s2;
            }
            bs[b] = ((r[0] + r[1]) + (r[2] + r[3])) + ((r[4] + r[5]) + (r[6] + r[7]));
        }
        float t16[16], t8[8], t4[4], t2[2];
        for (int i = 0; i < 16; ++i) t16[i] = bs[2 * i] + bs[2 * i + 1];
        for (int i = 0; i < 8; ++i) t8[i] = t16[2 * i] + t16[2 * i + 1];
        for (int i = 0; i < 4; ++i) t4[i] = t8[2 * i] + t8[2 * i + 1];
        for (int i = 0; i < 2; ++i) t2[i] = t4[2 * i] + t4[2 * i + 1];
        ssum_sh = t2[0] + t2[1];
    }
    __syncthreads();
    if (t < SLOTS) {
        float w = (t < n) ? (float)((double)evs[t] / (double)ssum_sh) : 0.f;
        wsel[t * NPIX + p] = w;
        isel[t * NPIX + p] = (t < n) ? slotj[t] : 0;
    }
}

// ---------------- gather: att@vals row — ascending-j fp32 FMA, 8 slots ----------

__global__ void gather_np_kernel(const float* __restrict__ V,
                                 const int* __restrict__ isel, const float* __restrict__ wsel,
                                 float* __restrict__ out, int CV) {
    int g = blockIdx.x * 256 + threadIdx.x;
    int p = g & (NPIX - 1);
    int c = g >> 12;
    if (c >= CV) return;
    const float* Vc = V + (size_t)c * NPIX;
    float s = 0.f;
#pragma unroll
    for (int tt = 0; tt < SLOTS; ++tt) {
        float w = wsel[tt * NPIX + p];
        int j = isel[tt * NPIX + p];
        s = fmaf(w, Vc[j], s);   // zero-weight slots: fma(0,v,s)=s exact
    }
    out[(size_t)c * NPIX + p] = s;
}

// ---------------- launch ----------------

extern "C" void kernel_launch(void* const* d_in, const int* in_sizes, int n_in,
                              void* d_out, int out_size, void* d_ws, size_t ws_size,
                              hipStream_t stream) {
    const float* ip = (const float*)d_in[0];   // inp_cont   [256][4096]
    const float* pp = (const float*)d_in[2];   // peers_cont [256][4096]
    const float* ps = (const float*)d_in[3];   // peers_style[512][4096]
    const float* w1c = (const float*)d_in[4];
    const float* b1c = (const float*)d_in[5];
    const float* g1c = (const float*)d_in[6];
    const float* be1c = (const float*)d_in[7];
    const float* m1c = (const float*)d_in[8];
    const float* v1c = (const float*)d_in[9];
    const float* w2c = (const float*)d_in[10];
    const float* b2c = (const float*)d_in[11];
    const float* g2c = (const float*)d_in[12];
    const float* be2c = (const float*)d_in[13];
    const float* m2c = (const float*)d_in[14];
    const float* v2c = (const float*)d_in[15];
    const float* c1cw = (const float*)d_in[16];
    const float* c1cb = (const float*)d_in[17];
    const float* c2cw = (const float*)d_in[18];
    const float* c2cb = (const float*)d_in[19];
    const float* w1s = (const float*)d_in[20];
    const float* b1s = (const float*)d_in[21];
    const float* g1s = (const float*)d_in[22];
    const float* be1s = (const float*)d_in[23];
    const float* m1s = (const float*)d_in[24];
    const float* v1s = (const float*)d_in[25];
    const float* w2s = (const float*)d_in[26];
    const float* b2s = (const float*)d_in[27];
    const float* g2s = (const float*)d_in[28];
    const float* be2s = (const float*)d_in[29];
    const float* m2s = (const float*)d_in[30];
    const float* v2s = (const float*)d_in[31];
    const float* c1sw = (const float*)d_in[32];
    const float* c1sb = (const float*)d_in[33];
    const float* c2sw = (const float*)d_in[34];
    const float* c2sb = (const float*)d_in[35];

    float* out_cont = (float*)d_out;                 // [256][4096]
    float* out_sty = (float*)d_out + 256 * NPIX;     // [512][4096]

    // workspace layout (floats)
    float* ws = (float*)d_ws;
    float* QS   = ws + 0;
    float* KS   = ws + 4096;
    float* SKNQ = ws + 8192;
    float* SKNK = ws + 12288;
    float* WSEL = ws + 16384;           // 8*4096
    int*   ISEL = (int*)(ws + 49152);   // 8*4096
    float* H1A  = ws + 81920;           // 256*4096
    float* H1B  = ws + 1130496;         // 256*4096
    float* H2A  = ws + 2179072;         // 128*4096
    float* H2B  = ws + 2703360;         // 128*4096
    float* D    = ws + 3227648;         // chunk_rows*4096

    // largest D chunk that fits (chunking only changes buffering, not results)
    size_t base = 3227648;
    int chunk = 256;
    if (ws_size >= (base + (size_t)4096 * NPIX) * 4) chunk = 4096;
    else if (ws_size >= (base + (size_t)2048 * NPIX) * 4) chunk = 2048;
    else if (ws_size >= (base + (size_t)1024 * NPIX) * 4) chunk = 1024;
    else if (ws_size >= (base + (size_t)512 * NPIX) * 4) chunk = 512;
    int nch = NPIX / chunk;

    // ---- stage 1: content distance, gather style ----
    gemm_bn_relu2_kernel<<<dim3(64, 2, 2), 256, 0, stream>>>(
        w1c, ip, pp, b1c, g1c, be1c, m1c, v1c, H1A, H1B, 128, 256);
    gemm_bn_relu2_kernel<<<dim3(64, 1, 2), 256, 0, stream>>>(
        w2c, H1A, H1B, b2c, g2c, be2c, m2c, v2c, H2A, H2B, 64, 128);
    dotk_np2_kernel<<<dim3(16, 1, 2), 256, 0, stream>>>(
        H2A, H2B, c1cw, c1cb, c2cw, c2cb, QS, KS, 64);
    skn_np2_kernel<<<dim3(32, 1, 2), 256, 0, stream>>>(ip, pp, SKNQ, SKNK, 256);
    for (int ch = 0; ch < nch; ++ch) {
        dist_np_kernel<<<dim3(32, chunk / 64), 256, 0, stream>>>(ip, pp, SKNQ, SKNK, D, 256, ch * chunk);
        row_select_np_kernel<<<chunk, 256, 0, stream>>>(D, QS, KS, ISEL, WSEL, ch * chunk);
    }
    gather_np_kernel<<<(512 * NPIX) / 256, 256, 0, stream>>>(ps, ISEL, WSEL, out_sty, 512);

    // ---- stage 2: style distance, gather content ----
    gemm_bn_relu2_kernel<<<dim3(64, 4, 2), 256, 0, stream>>>(
        w1s, out_sty, ps, b1s, g1s, be1s, m1s, v1s, H1A, H1B, 256, 512);
    gemm_bn_relu2_kernel<<<dim3(64, 2, 2), 256, 0, stream>>>(
        w2s, H1A, H1B, b2s, g2s, be2s, m2s, v2s, H2A, H2B, 128, 256);
    dotk_np2_kernel<<<dim3(16, 1, 2), 256, 0, stream>>>(
        H2A, H2B, c1sw, c1sb, c2sw, c2sb, QS, KS, 128);
    skn_np2_kernel<<<dim3(64, 1, 2), 256, 0, stream>>>(out_sty, ps, SKNQ, SKNK, 512);
    for (int ch = 0; ch < nch; ++ch) {
        dist_np_kernel<<<dim3(32, chunk / 64), 256, 0, stream>>>(out_sty, ps, SKNQ, SKNK, D, 512, ch * chunk);
        row_select_np_kernel<<<chunk, 256, 0, stream>>>(D, QS, KS, ISEL, WSEL, ch * chunk);
    }
    gather_np_kernel<<<(256 * NPIX) / 256, 256, 0, stream>>>(pp, ISEL, WSEL, out_cont, 256);
}

// Round 19
// 535.214 us; speedup vs baseline: 1.0498x; 1.0498x over previous
//
#include <hip/hip_runtime.h>
#include <math.h>

#pragma clang fp contract(off)

#define NPIX 4096
#define BIGF 3.0e38f
#define SLOTS 8

// ---------------- helpers ----------------

// value-only sorted insert (ascending) into top-5
__device__ __forceinline__ void ins5v(float v, float dl[5]) {
    if (v >= dl[4]) return;
    dl[4] = v;
#pragma unroll
    for (int u = 4; u > 0; --u)
        if (dl[u] < dl[u - 1]) { float t_ = dl[u]; dl[u] = dl[u - 1]; dl[u - 1] = t_; }
}

// np.logaddexp(x, 0) emulation: scalar libm path, fp64-rounded (≈correctly rounded fp32)
__device__ __forceinline__ float softplus_np(float x) {
    if (x > 0.f) {
        float ef = (float)exp((double)(-x));
        return x + (float)log1p((double)ef);
    } else if (x < 0.f) {
        float ef = (float)exp((double)x);
        return (float)log1p((double)ef);
    }
    return 0.69314718055994530942f;
}

// ---------------- fused GEMM + BN + relu (np op order), z-batched pair ----------

__global__ __launch_bounds__(256) void gemm_bn_relu2_kernel(
    const float* __restrict__ W,
    const float* __restrict__ Xa, const float* __restrict__ Xb,
    const float* __restrict__ b, const float* __restrict__ g,
    const float* __restrict__ be, const float* __restrict__ m,
    const float* __restrict__ v,
    float* __restrict__ Ha, float* __restrict__ Hb, int M, int K) {
    const float* X = blockIdx.z ? Xb : Xa;
    float* H = blockIdx.z ? Hb : Ha;
    __shared__ float Ws[16][68];
    __shared__ float Xs[16][68];
    int t = threadIdx.x;
    int tx = t & 15, ty = t >> 4;
    int n0 = blockIdx.x * 64, m0 = blockIdx.y * 64;
    int wm = t >> 2, wk = (t & 3) * 4;
    int xk = t >> 4, xn = (t & 15) * 4;
    float acc[4][4] = {};
    for (int k0 = 0; k0 < K; k0 += 16) {
        float4 wv = *(const float4*)&W[(size_t)(m0 + wm) * K + k0 + wk];
        Ws[wk + 0][wm] = wv.x; Ws[wk + 1][wm] = wv.y;
        Ws[wk + 2][wm] = wv.z; Ws[wk + 3][wm] = wv.w;
        *(float4*)&Xs[xk][xn] = *(const float4*)&X[(size_t)(k0 + xk) * NPIX + n0 + xn];
        __syncthreads();
#pragma unroll
        for (int kk = 0; kk < 16; ++kk) {
            float4 a4 = *(float4*)&Ws[kk][ty * 4];
            float4 b4 = *(float4*)&Xs[kk][tx * 4];
            float ar[4] = {a4.x, a4.y, a4.z, a4.w};
            float br[4] = {b4.x, b4.y, b4.z, b4.w};
#pragma unroll
            for (int i = 0; i < 4; ++i)
#pragma unroll
                for (int j = 0; j < 4; ++j)
                    acc[i][j] = fmaf(ar[i], br[j], acc[i][j]);
        }
        __syncthreads();
    }
#pragma unroll
    for (int i = 0; i < 4; ++i) {
        int mrow = m0 + ty * 4 + i;
        float bb = b[mrow];
        float mm_ = m[mrow];
        float gg = g[mrow];
        float vv = v[mrow] + 1e-5f;
        float ss = (float)sqrt((double)vv);
        float bee = be[mrow];
        float o[4];
#pragma unroll
        for (int j = 0; j < 4; ++j) {
            float t0 = acc[i][j] + bb;
            t0 = t0 - mm_;
            t0 = t0 * gg;
            t0 = (float)((double)t0 / (double)ss);
            t0 = t0 + bee;
            o[j] = fmaxf(t0, 0.f);
        }
        *(float4*)&H[(size_t)mrow * NPIX + n0 + tx * 4] = *(float4*)&o[0];
    }
}

// ---------------- fused util: {dotk_q, dotk_k, skn_q, skn_k} via blockIdx.y -------
// dotk: sequential fp32 FMA over c + bias at end (np/BLAS order).
// skn: numpy pairwise 128-block sum of fp32 squares, blocks combined in fixed tree.

__global__ void util_np_kernel(
    const float* __restrict__ H2A, const float* __restrict__ H2B,
    const float* __restrict__ cwa, const float* __restrict__ cba,
    const float* __restrict__ cwb, const float* __restrict__ cbb,
    float* __restrict__ QS, float* __restrict__ KS, int CH,
    const float* __restrict__ Yq, const float* __restrict__ Yk,
    float* __restrict__ SKNQ, float* __restrict__ SKNK, int CY) {
    int task = blockIdx.y;
    int t = threadIdx.x;
    if (task < 2) {
        if (blockIdx.x >= 16) return;
        const float* H = task ? H2B : H2A;
        const float* cw = task ? cwb : cwa;
        const float* cb = task ? cbb : cba;
        float* out = task ? KS : QS;
        int p = blockIdx.x * 256 + t;
        float s = 0.f;
#pragma unroll 8
        for (int c = 0; c < CH; ++c) s = fmaf(H[(size_t)c * NPIX + p], cw[c], s);
        out[p] = s + cb[0];
    } else {
        const float* Y = (task == 2) ? Yq : Yk;
        float* skn = (task == 2) ? SKNQ : SKNK;
        int nb = CY >> 7;                // 2 or 4
        int ppb = 256 / nb;              // p's per block
        if (blockIdx.x * ppb >= NPIX) return;
        int pl = t % ppb;
        int b = t / ppb;
        int p = blockIdx.x * ppb + pl;
        __shared__ float sh[256];
        int c0 = b << 7;
        float r[8];
#pragma unroll
        for (int k = 0; k < 8; ++k) {
            float y = Y[(size_t)(c0 + k) * NPIX + p];
            r[k] = y * y;
        }
        for (int i = 8; i < 128; i += 8) {
#pragma unroll
            for (int k = 0; k < 8; ++k) {
                float y = Y[(size_t)(c0 + i + k) * NPIX + p];
                float q = y * y;
                r[k] = r[k] + q;
            }
        }
        sh[b * ppb + pl] = ((r[0] + r[1]) + (r[2] + r[3])) + ((r[4] + r[5]) + (r[6] + r[7]));
        __syncthreads();
        if (b == 0) {
            float s;
            if (nb == 2) s = sh[pl] + sh[ppb + pl];
            else s = (sh[pl] + sh[ppb + pl]) + (sh[2 * ppb + pl] + sh[3 * ppb + pl]);
            skn[p] = s;
        }
    }
}

// ---------------- distance: np-exact fp32, 64x128 tile, 4x8 micro ----------
// R16's proven variant: prefetch-into-registers, single LDS buffer, slot-padded
// Ys (all hot-loop LDS reads <=2-way). Per (q,k): fp32 FMA over c ascending —
// identical arithmetic to R10's passing kernel.

__global__ __launch_bounds__(256) void dist_np_kernel(
    const float* __restrict__ XT, const float* __restrict__ YT,
    const float* __restrict__ sknq, const float* __restrict__ sknk,
    float* __restrict__ D, int C, int qbase) {
    __shared__ float Xs[16][68];
    __shared__ float Ys[16][16][12];
    int t = threadIdx.x;
    int tx = t & 15, ty = t >> 4;
    int q0 = qbase + blockIdx.y * 64;
    int k0 = blockIdx.x * 128;
    float acc[4][8] = {};
    // prologue: first staging loads
    float4 xr = *(const float4*)&XT[(size_t)ty * NPIX + q0 + tx * 4];
    float4 yr0 = *(const float4*)&YT[(size_t)ty * NPIX + k0 + tx * 8];
    float4 yr1 = *(const float4*)&YT[(size_t)ty * NPIX + k0 + tx * 8 + 4];
    for (int c0 = 0; c0 < C; c0 += 16) {
        *(float4*)&Xs[ty][tx * 4] = xr;
        *(float4*)&Ys[ty][tx][0] = yr0;
        *(float4*)&Ys[ty][tx][4] = yr1;
        __syncthreads();
        if (c0 + 16 < C) {   // prefetch next tile; latency hides under compute
            xr = *(const float4*)&XT[(size_t)(c0 + 16 + ty) * NPIX + q0 + tx * 4];
            yr0 = *(const float4*)&YT[(size_t)(c0 + 16 + ty) * NPIX + k0 + tx * 8];
            yr1 = *(const float4*)&YT[(size_t)(c0 + 16 + ty) * NPIX + k0 + tx * 8 + 4];
        }
#pragma unroll
        for (int kk = 0; kk < 16; ++kk) {
            float4 a4 = *(float4*)&Xs[kk][ty * 4];
            float4 b40 = *(float4*)&Ys[kk][tx][0];
            float4 b41 = *(float4*)&Ys[kk][tx][4];
            float ar[4] = {a4.x, a4.y, a4.z, a4.w};
            float br[8] = {b40.x, b40.y, b40.z, b40.w, b41.x, b41.y, b41.z, b41.w};
#pragma unroll
            for (int i = 0; i < 4; ++i)
#pragma unroll
                for (int j = 0; j < 8; ++j)
                    acc[i][j] = fmaf(ar[i], br[j], acc[i][j]);
        }
        __syncthreads();
    }
    float sk8[8];
    *(float4*)&sk8[0] = *(const float4*)&sknk[k0 + tx * 8];
    *(float4*)&sk8[4] = *(const float4*)&sknk[k0 + tx * 8 + 4];
#pragma unroll
    for (int i = 0; i < 4; ++i) {
        float sq = sknq[q0 + ty * 4 + i];
        int lq = q0 - qbase + ty * 4 + i;
        float tmp[8];
#pragma unroll
        for (int j = 0; j < 8; ++j) {
            float A = sq + sk8[j];
            float B = 2.0f * acc[i][j];
            float d2 = A - B;
            float dc = fmaxf(d2, 0.f);
            tmp[j] = (float)sqrt((double)dc);
        }
        *(float4*)&D[(size_t)lq * NPIX + k0 + tx * 8] = *(float4*)&tmp[0];
        *(float4*)&D[(size_t)lq * NPIX + k0 + tx * 8 + 4] = *(float4*)&tmp[4];
    }
}

// ---------------- selection + np-softmax weights ----------------
// float4 D reads (thread->value assignment free: kth is a multiset statistic,
// kept set re-sorted by index); 3-level merge tree. 8 slots (n<=8 verified).

__global__ __launch_bounds__(256) void row_select_np_kernel(
    const float* __restrict__ D, const float* __restrict__ qs, const float* __restrict__ ks,
    int* __restrict__ isel, float* __restrict__ wsel, int qbase) {
    int p = qbase + blockIdx.x;
    const float* drow = D + (size_t)blockIdx.x * NPIX;
    int t = threadIdx.x;
    __shared__ float tops[256][5];
    __shared__ float l2[64][5];
    __shared__ float l3[16][5];
    __shared__ float kth_sh;
    __shared__ int cnt;
    __shared__ int slotj[16];
    __shared__ int n_sh;
    __shared__ float as_[16];
    __shared__ float evs[16];
    __shared__ float mx_sh, ssum_sh;

    if (t == 0) cnt = 0;
    float vcache[16];
    *(float4*)&vcache[0] = *(const float4*)&drow[t * 16];
    *(float4*)&vcache[4] = *(const float4*)&drow[t * 16 + 4];
    *(float4*)&vcache[8] = *(const float4*)&drow[t * 16 + 8];
    *(float4*)&vcache[12] = *(const float4*)&drow[t * 16 + 12];
    float dl[5] = {BIGF, BIGF, BIGF, BIGF, BIGF};
#pragma unroll
    for (int u = 0; u < 16; ++u) ins5v(vcache[u], dl);
#pragma unroll
    for (int u = 0; u < 5; ++u) tops[t][u] = dl[u];
    __syncthreads();
    if (t < 64) {
        float md[5] = {BIGF, BIGF, BIGF, BIGF, BIGF};
        for (int i = 0; i < 4; ++i)
            for (int u = 0; u < 5; ++u) ins5v(tops[t * 4 + i][u], md);
#pragma unroll
        for (int u = 0; u < 5; ++u) l2[t][u] = md[u];
    }
    __syncthreads();
    if (t < 16) {
        float md[5] = {BIGF, BIGF, BIGF, BIGF, BIGF};
        for (int i = 0; i < 4; ++i)
            for (int u = 0; u < 5; ++u) ins5v(l2[t * 4 + i][u], md);
#pragma unroll
        for (int u = 0; u < 5; ++u) l3[t][u] = md[u];
    }
    __syncthreads();
    if (t == 0) {
        float md[5] = {BIGF, BIGF, BIGF, BIGF, BIGF};
        for (int i = 0; i < 16; ++i)
            for (int u = 0; u < 5; ++u) ins5v(l3[i][u], md);
        kth_sh = md[4];
    }
    __syncthreads();
    float kth = kth_sh;
#pragma unroll
    for (int u = 0; u < 16; ++u) {
        if (vcache[u] <= kth) {
            int s = atomicAdd(&cnt, 1);
            if (s < 16) slotj[s] = t * 16 + u;
        }
    }
    __syncthreads();
    if (t == 0) {
        int n = cnt < 16 ? cnt : 16;
        for (int a = 1; a < n; ++a) {
            int key = slotj[a]; int b = a - 1;
            while (b >= 0 && slotj[b] > key) { slotj[b + 1] = slotj[b]; --b; }
            slotj[b + 1] = key;
        }
        n_sh = n;
    }
    __syncthreads();
    int n = n_sh;
    if (t < n) {
        float x = qs[p] + ks[slotj[t]];
        as_[t] = softplus_np(x);          // same formula, same input -> same bits
    }
    __syncthreads();
    if (t == 0) {
        float mx = -BIGF;
        for (int s = 0; s < n; ++s) mx = fmaxf(mx, as_[s]);
        mx_sh = mx;
    }
    __syncthreads();
    if (t < n) evs[t] = (float)exp((double)(as_[t] - mx_sh));
    __syncthreads();
    if (t == 0) {
        // numpy pairwise-tree sum over the sparse 4096-row (zeros absorb exactly)
        float bs[32];
        for (int i = 0; i < 32; ++i) bs[i] = 0.f;
        int s2 = 0;
        while (s2 < n) {
            int b = slotj[s2] >> 7;
            float r[8] = {0.f, 0.f, 0.f, 0.f, 0.f, 0.f, 0.f, 0.f};
            while (s2 < n && (slotj[s2] >> 7) == b) {
                int res = slotj[s2] & 7;
                r[res] = r[res] + evs[s2];
                ++s2;
            }
            bs[b] = ((r[0] + r[1]) + (r[2] + r[3])) + ((r[4] + r[5]) + (r[6] + r[7]));
        }
        float t16[16], t8[8], t4[4], t2[2];
        for (int i = 0; i < 16; ++i) t16[i] = bs[2 * i] + bs[2 * i + 1];
        for (int i = 0; i < 8; ++i) t8[i] = t16[2 * i] + t16[2 * i + 1];
        for (int i = 0; i < 4; ++i) t4[i] = t8[2 * i] + t8[2 * i + 1];
        for (int i = 0; i < 2; ++i) t2[i] = t4[2 * i] + t4[2 * i + 1];
        ssum_sh = t2[0] + t2[1];
    }
    __syncthreads();
    if (t < SLOTS) {
        float w = (t < n) ? (float)((double)evs[t] / (double)ssum_sh) : 0.f;
        wsel[t * NPIX + p] = w;
        isel[t * NPIX + p] = (t < n) ? slotj[t] : 0;
    }
}

// ---------------- gather: att@vals row — ascending-j fp32 FMA, 8 slots ----------

__global__ void gather_np_kernel(const float* __restrict__ V,
                                 const int* __restrict__ isel, const float* __restrict__ wsel,
                                 float* __restrict__ out, int CV) {
    int g = blockIdx.x * 256 + threadIdx.x;
    int p = g & (NPIX - 1);
    int c = g >> 12;
    if (c >= CV) return;
    const float* Vc = V + (size_t)c * NPIX;
    float s = 0.f;
#pragma unroll
    for (int tt = 0; tt < SLOTS; ++tt) {
        float w = wsel[tt * NPIX + p];
        int j = isel[tt * NPIX + p];
        s = fmaf(w, Vc[j], s);   // zero-weight slots: fma(0,v,s)=s exact
    }
    out[(size_t)c * NPIX + p] = s;
}

// ---------------- launch ----------------

extern "C" void kernel_launch(void* const* d_in, const int* in_sizes, int n_in,
                              void* d_out, int out_size, void* d_ws, size_t ws_size,
                              hipStream_t stream) {
    const float* ip = (const float*)d_in[0];   // inp_cont   [256][4096]
    const float* pp = (const float*)d_in[2];   // peers_cont [256][4096]
    const float* ps = (const float*)d_in[3];   // peers_style[512][4096]
    const float* w1c = (const float*)d_in[4];
    const float* b1c = (const float*)d_in[5];
    const float* g1c = (const float*)d_in[6];
    const float* be1c = (const float*)d_in[7];
    const float* m1c = (const float*)d_in[8];
    const float* v1c = (const float*)d_in[9];
    const float* w2c = (const float*)d_in[10];
    const float* b2c = (const float*)d_in[11];
    const float* g2c = (const float*)d_in[12];
    const float* be2c = (const float*)d_in[13];
    const float* m2c = (const float*)d_in[14];
    const float* v2c = (const float*)d_in[15];
    const float* c1cw = (const float*)d_in[16];
    const float* c1cb = (const float*)d_in[17];
    const float* c2cw = (const float*)d_in[18];
    const float* c2cb = (const float*)d_in[19];
    const float* w1s = (const float*)d_in[20];
    const float* b1s = (const float*)d_in[21];
    const float* g1s = (const float*)d_in[22];
    const float* be1s = (const float*)d_in[23];
    const float* m1s = (const float*)d_in[24];
    const float* v1s = (const float*)d_in[25];
    const float* w2s = (const float*)d_in[26];
    const float* b2s = (const float*)d_in[27];
    const float* g2s = (const float*)d_in[28];
    const float* be2s = (const float*)d_in[29];
    const float* m2s = (const float*)d_in[30];
    const float* v2s = (const float*)d_in[31];
    const float* c1sw = (const float*)d_in[32];
    const float* c1sb = (const float*)d_in[33];
    const float* c2sw = (const float*)d_in[34];
    const float* c2sb = (const float*)d_in[35];

    float* out_cont = (float*)d_out;                 // [256][4096]
    float* out_sty = (float*)d_out + 256 * NPIX;     // [512][4096]

    // workspace layout (floats)
    float* ws = (float*)d_ws;
    float* QS   = ws + 0;
    float* KS   = ws + 4096;
    float* SKNQ = ws + 8192;
    float* SKNK = ws + 12288;
    float* WSEL = ws + 16384;           // 8*4096
    int*   ISEL = (int*)(ws + 49152);   // 8*4096
    float* H1A  = ws + 81920;           // 256*4096
    float* H1B  = ws + 1130496;         // 256*4096
    float* H2A  = ws + 2179072;         // 128*4096
    float* H2B  = ws + 2703360;         // 128*4096
    float* D    = ws + 3227648;         // chunk_rows*4096

    // largest D chunk that fits (chunking only changes buffering, not results)
    size_t base = 3227648;
    int chunk = 256;
    if (ws_size >= (base + (size_t)4096 * NPIX) * 4) chunk = 4096;
    else if (ws_size >= (base + (size_t)2048 * NPIX) * 4) chunk = 2048;
    else if (ws_size >= (base + (size_t)1024 * NPIX) * 4) chunk = 1024;
    else if (ws_size >= (base + (size_t)512 * NPIX) * 4) chunk = 512;
    int nch = NPIX / chunk;

    // ---- stage 1: content distance, gather style ----
    gemm_bn_relu2_kernel<<<dim3(64, 2, 2), 256, 0, stream>>>(
        w1c, ip, pp, b1c, g1c, be1c, m1c, v1c, H1A, H1B, 128, 256);
    gemm_bn_relu2_kernel<<<dim3(64, 1, 2), 256, 0, stream>>>(
        w2c, H1A, H1B, b2c, g2c, be2c, m2c, v2c, H2A, H2B, 64, 128);
    util_np_kernel<<<dim3(64, 4), 256, 0, stream>>>(
        H2A, H2B, c1cw, c1cb, c2cw, c2cb, QS, KS, 64,
        ip, pp, SKNQ, SKNK, 256);
    for (int ch = 0; ch < nch; ++ch) {
        dist_np_kernel<<<dim3(32, chunk / 64), 256, 0, stream>>>(ip, pp, SKNQ, SKNK, D, 256, ch * chunk);
        row_select_np_kernel<<<chunk, 256, 0, stream>>>(D, QS, KS, ISEL, WSEL, ch * chunk);
    }
    gather_np_kernel<<<(512 * NPIX) / 256, 256, 0, stream>>>(ps, ISEL, WSEL, out_sty, 512);

    // ---- stage 2: style distance, gather content ----
    gemm_bn_relu2_kernel<<<dim3(64, 4, 2), 256, 0, stream>>>(
        w1s, out_sty, ps, b1s, g1s, be1s, m1s, v1s, H1A, H1B, 256, 512);
    gemm_bn_relu2_kernel<<<dim3(64, 2, 2), 256, 0, stream>>>(
        w2s, H1A, H1B, b2s, g2s, be2s, m2s, v2s, H2A, H2B, 128, 256);
    util_np_kernel<<<dim3(64, 4), 256, 0, stream>>>(
        H2A, H2B, c1sw, c1sb, c2sw, c2sb, QS, KS, 128,
        out_sty, ps, SKNQ, SKNK, 512);
    for (int ch = 0; ch < nch; ++ch) {
        dist_np_kernel<<<dim3(32, chunk / 64), 256, 0, stream>>>(out_sty, ps, SKNQ, SKNK, D, 512, ch * chunk);
        row_select_np_kernel<<<chunk, 256, 0, stream>>>(D, QS, KS, ISEL, WSEL, ch * chunk);
    }
    gather_np_kernel<<<(256 * NPIX) / 256, 256, 0, stream>>>(pp, ISEL, WSEL, out_cont, 256);
}